// Round 1
// baseline (1213.204 us; speedup 1.0000x reference)
//
#include <hip/hip_runtime.h>

// ---------------------------------------------------------------------------
// GAT 2-layer forward on MI355X. Round 1: correctness-first implementation.
// Pipeline:
//   fold weights -> encoder GEMMs -> h1 = x@W1^T (bf16) -> att dots ->
//   build edges (+loops) -> CSR by dst (count/scan/scatter) ->
//   conv1 per-dst softmax+aggregate -> x2 (bf16) -> h2 = x2@W2^T ->
//   att dots2 -> conv2 aggregate -> x3 -> logits GEMM -> d_out
// ---------------------------------------------------------------------------

#define NEG_SLOPE 0.2f

__device__ __forceinline__ float bf2f(unsigned short u) {
  return __uint_as_float(((unsigned)u) << 16);
}
__device__ __forceinline__ unsigned short f2bf(float f) {
  unsigned u = __float_as_uint(f);
  u += 0x7fffu + ((u >> 16) & 1u);   // round-to-nearest-even
  return (unsigned short)(u >> 16);
}

// ---------------------------------------------------------------------------
// Fold W_node [256,128] -> Wn_f [256,64] (sum halves), W_col [256,256] -> [256,128]
__global__ void fold_weights(const float* __restrict__ Wn, const float* __restrict__ Wc,
                             float* __restrict__ Wn_f, float* __restrict__ Wc_f) {
  int idx = blockIdx.x * 256 + threadIdx.x;
  if (idx < 256 * 64) {
    int o = idx >> 6, j = idx & 63;
    Wn_f[idx] = Wn[o * 128 + j] + Wn[o * 128 + 64 + j];
  }
  idx -= 256 * 64;
  if (idx >= 0 && idx < 256 * 128) {
    int o = idx >> 7, j = idx & 127;
    Wc_f[idx] = Wc[o * 256 + j] + Wc[o * 256 + 128 + j];
  }
}

// ---------------------------------------------------------------------------
// Generic tiled GEMM, B^T layout: C[m,n] = sum_k A[m,k] * W[n,k]  (+bias,relu)
// A: [M,K] row-major (f32 or bf16), W: [Nout,K] row-major f32.
// Tile 64x64, BK=16, 256 threads, 4x4 outputs/thread.
// Requires: K % 16 == 0, Nout % 64 == 0 (true for all calls here).
template <bool A_BF16, bool C_BF16, bool RELU, bool BIAS>
__global__ __launch_bounds__(256) void gemm_bt(const void* __restrict__ Av,
                                               const float* __restrict__ W,
                                               const float* __restrict__ bias,
                                               void* __restrict__ Cv,
                                               int M, int K, int Nout) {
  const float* Af = (const float*)Av;
  const unsigned short* Ab = (const unsigned short*)Av;
  float* Cf = (float*)Cv;
  unsigned short* Cb = (unsigned short*)Cv;

  __shared__ float As[16][65];
  __shared__ float Bs[16][65];

  int tid = threadIdx.x;
  int m0 = blockIdx.y * 64, n0 = blockIdx.x * 64;
  int tx = tid & 15, ty = tid >> 4;
  float acc[4][4] = {};

  for (int k0 = 0; k0 < K; k0 += 16) {
#pragma unroll
    for (int l = 0; l < 4; ++l) {
      int idx = tid + l * 256;
      int ar = idx >> 4, ac = idx & 15;
      int row = m0 + ar;
      float v = 0.f;
      if (row < M) {
        size_t a = (size_t)row * K + k0 + ac;
        v = A_BF16 ? bf2f(Ab[a]) : Af[a];
      }
      As[ac][ar] = v;
    }
#pragma unroll
    for (int l = 0; l < 4; ++l) {
      int idx = tid + l * 256;
      int nr = idx >> 4, kc = idx & 15;
      Bs[kc][nr] = W[(size_t)(n0 + nr) * K + k0 + kc];
    }
    __syncthreads();
#pragma unroll
    for (int kk = 0; kk < 16; ++kk) {
      float a[4], b[4];
#pragma unroll
      for (int i = 0; i < 4; ++i) a[i] = As[kk][ty + 16 * i];
#pragma unroll
      for (int j = 0; j < 4; ++j) b[j] = Bs[kk][tx + 16 * j];
#pragma unroll
      for (int i = 0; i < 4; ++i)
#pragma unroll
        for (int j = 0; j < 4; ++j) acc[i][j] += a[i] * b[j];
    }
    __syncthreads();
  }

#pragma unroll
  for (int i = 0; i < 4; ++i) {
    int row = m0 + ty + 16 * i;
    if (row >= M) continue;
#pragma unroll
    for (int j = 0; j < 4; ++j) {
      int col = n0 + tx + 16 * j;
      float v = acc[i][j];
      if (BIAS) v += bias[col];
      if (RELU) v = fmaxf(v, 0.f);
      size_t o = (size_t)row * Nout + col;
      if (C_BF16) Cb[o] = f2bf(v); else Cf[o] = v;
    }
  }
}

// ---------------------------------------------------------------------------
// a_s[n,h] = dot(h[n,h,:], att_s[h,:]); a_d likewise. One wave per (n,h), C=256.
template <bool BF16>
__global__ __launch_bounds__(256) void att_dots(const void* __restrict__ hv,
                                                const float* __restrict__ att_s,
                                                const float* __restrict__ att_d,
                                                float* __restrict__ a_s,
                                                float* __restrict__ a_d,
                                                int N, int H) {
  int wid = (blockIdx.x * 256 + threadIdx.x) >> 6;
  int lane = threadIdx.x & 63;
  if (wid >= N * H) return;
  int n = wid / H, hh = wid - n * H;
  int c = lane * 4;
  float v[4];
  if (BF16) {
    const unsigned short* row = (const unsigned short*)hv + (size_t)n * H * 256 + hh * 256;
    ushort4 r = *(const ushort4*)(row + c);
    v[0] = bf2f(r.x); v[1] = bf2f(r.y); v[2] = bf2f(r.z); v[3] = bf2f(r.w);
  } else {
    const float* row = (const float*)hv + (size_t)n * H * 256 + hh * 256;
    float4 r = *(const float4*)(row + c);
    v[0] = r.x; v[1] = r.y; v[2] = r.z; v[3] = r.w;
  }
  float4 sa = *(const float4*)(att_s + hh * 256 + c);
  float4 da = *(const float4*)(att_d + hh * 256 + c);
  float s1 = v[0] * sa.x + v[1] * sa.y + v[2] * sa.z + v[3] * sa.w;
  float s2 = v[0] * da.x + v[1] * da.y + v[2] * da.z + v[3] * da.w;
#pragma unroll
  for (int off = 32; off; off >>= 1) {
    s1 += __shfl_down(s1, off);
    s2 += __shfl_down(s2, off);
  }
  if (lane == 0) { a_s[wid] = s1; a_d[wid] = s2; }
}

// ---------------------------------------------------------------------------
// Edge materialization: int64-vs-int32 auto-detect, append self loops.
__global__ void build_edges(const void* __restrict__ edges_raw, int E, int N,
                            int* __restrict__ esrc, int* __restrict__ edst, int E1) {
  const long long* p64 = (const long long*)edges_raw;
  const int* p32 = (const int*)edges_raw;
  bool is64 = true;
#pragma unroll
  for (int i = 0; i < 8; ++i) {
    long long v = p64[i];
    if (v < 0 || v >= N) is64 = false;
  }
  int idx = blockIdx.x * 256 + threadIdx.x;
  if (idx >= E1) return;
  if (idx < E) {
    long long s, d;
    if (is64) { s = p64[idx]; d = p64[E + idx]; }
    else      { s = p32[idx]; d = p32[E + idx]; }
    esrc[idx] = (int)s;
    edst[idx] = (int)d;
  } else {
    int n = idx - E;
    esrc[idx] = n;
    edst[idx] = n;
  }
}

__global__ void count_edges(const int* __restrict__ esrc, const int* __restrict__ edst,
                            int* __restrict__ cnt1, int* __restrict__ cnt2, int E1) {
  int e = blockIdx.x * 256 + threadIdx.x;
  if (e >= E1) return;
  atomicAdd(&cnt1[edst[e]], 1);
  atomicAdd(&cnt2[esrc[e]], 1);
}

__device__ void scan_one(const int* __restrict__ cnt, int* __restrict__ indptr,
                         int* __restrict__ cur, int N, int* buf) {
  int t = threadIdx.x;
  int running = 0;
  for (int base = 0; base < N; base += 1024) {
    int v = (base + t < N) ? cnt[base + t] : 0;
    buf[t] = v;
    __syncthreads();
    for (int off = 1; off < 1024; off <<= 1) {
      int x = (t >= off) ? buf[t - off] : 0;
      __syncthreads();
      buf[t] += x;
      __syncthreads();
    }
    int incl = buf[t];
    if (base + t < N) {
      int excl = running + incl - v;
      indptr[base + t] = excl;
      cur[base + t] = excl;
    }
    int tot = buf[1023];
    __syncthreads();
    running += tot;
  }
  if (t == 0) indptr[N] = running;
  __syncthreads();
}

__global__ __launch_bounds__(1024) void scan2_kernel(const int* cnt1, int* indptr1, int* cur1,
                                                     const int* cnt2, int* indptr2, int* cur2,
                                                     int N) {
  __shared__ int buf[1024];
  scan_one(cnt1, indptr1, cur1, N, buf);
  scan_one(cnt2, indptr2, cur2, N, buf);
}

__global__ void scatter_edges(const int* __restrict__ esrc, const int* __restrict__ edst,
                              int* __restrict__ cur1, int* __restrict__ cur2,
                              int* __restrict__ eidx1, int* __restrict__ eidx2, int E1) {
  int e = blockIdx.x * 256 + threadIdx.x;
  if (e >= E1) return;
  int p1 = atomicAdd(&cur1[edst[e]], 1);
  eidx1[p1] = e;
  int p2 = atomicAdd(&cur2[esrc[e]], 1);
  eidx2[p2] = e;
}

// ---------------------------------------------------------------------------
// conv1: per-dst softmax (8 heads) + weighted aggregation of h1[src] (bf16 2048-wide).
// One block (256 thr) per dst; thread t owns channels [8t, 8t+8) -> head = t>>5.
__global__ __launch_bounds__(256) void conv1_agg(const unsigned short* __restrict__ h1,
                                                 const float* __restrict__ a_s,
                                                 const float* __restrict__ a_d,
                                                 const int* __restrict__ esrc,
                                                 const int* __restrict__ indptr,
                                                 const int* __restrict__ eidx,
                                                 const float* __restrict__ b1,
                                                 unsigned short* __restrict__ x2) {
  int dst = blockIdx.x, tid = threadIdx.x;
  int start = indptr[dst];
  int deg = indptr[dst + 1] - start;
  __shared__ float m_sh[8], d_sh[8];
  __shared__ float al_sh[64 * 8];
  __shared__ int src_sh[64];
  int lane = tid & 63, wave = tid >> 6;

  // phase 1: per-head max & expsum (wave w handles heads w, w+4)
  for (int h = wave; h < 8; h += 4) {
    float ad = a_d[dst * 8 + h];
    float mx = -1e30f;
    for (int j = lane; j < deg; j += 64) {
      int e = eidx[start + j];
      float ev = a_s[esrc[e] * 8 + h] + ad;
      ev = ev > 0.f ? ev : NEG_SLOPE * ev;
      mx = fmaxf(mx, ev);
    }
#pragma unroll
    for (int off = 32; off; off >>= 1) mx = fmaxf(mx, __shfl_down(mx, off));
    mx = __shfl(mx, 0);
    float sm = 0.f;
    for (int j = lane; j < deg; j += 64) {
      int e = eidx[start + j];
      float ev = a_s[esrc[e] * 8 + h] + ad;
      ev = ev > 0.f ? ev : NEG_SLOPE * ev;
      sm += __expf(ev - mx);
    }
#pragma unroll
    for (int off = 32; off; off >>= 1) sm += __shfl_down(sm, off);
    if (lane == 0) { m_sh[h] = mx; d_sh[h] = sm + 1e-16f; }
  }
  __syncthreads();

  float acc[8] = {0.f, 0.f, 0.f, 0.f, 0.f, 0.f, 0.f, 0.f};
  int myhead = tid >> 5;
  for (int base = 0; base < deg; base += 64) {
    int cnt = min(64, deg - base);
    for (int t = tid; t < cnt * 8; t += 256) {
      int j = t >> 3, h = t & 7;
      int e = eidx[start + base + j];
      int s = esrc[e];
      if (h == 0) src_sh[j] = s;
      float ev = a_s[s * 8 + h] + a_d[dst * 8 + h];
      ev = ev > 0.f ? ev : NEG_SLOPE * ev;
      al_sh[j * 8 + h] = __expf(ev - m_sh[h]) / d_sh[h];
    }
    __syncthreads();
    for (int j = 0; j < cnt; ++j) {
      float al = al_sh[j * 8 + myhead];
      const float4* hp = (const float4*)(h1 + (size_t)src_sh[j] * 2048);
      float4 r = hp[tid];                     // 8 bf16, channels [8t,8t+8)
      const unsigned short* rb = (const unsigned short*)&r;
#pragma unroll
      for (int i = 0; i < 8; ++i) acc[i] += al * bf2f(rb[i]);
    }
    __syncthreads();
  }

  unsigned short outv[8];
#pragma unroll
  for (int i = 0; i < 8; ++i) {
    float v = acc[i] + b1[tid * 8 + i];
    outv[i] = f2bf(fmaxf(v, 0.f));
  }
  *((float4*)(x2 + (size_t)dst * 2048 + tid * 8)) = *((const float4*)outv);
}

// ---------------------------------------------------------------------------
// conv2: 1 head, 256-wide f32. One block per dst; thread t owns channel t.
// "other" = source array of the flipped edge (= conv1 dst array).
__global__ __launch_bounds__(256) void conv2_agg(const float* __restrict__ h2,
                                                 const float* __restrict__ a_s,
                                                 const float* __restrict__ a_d,
                                                 const int* __restrict__ other,
                                                 const int* __restrict__ indptr,
                                                 const int* __restrict__ eidx,
                                                 const float* __restrict__ b2,
                                                 float* __restrict__ x3) {
  int dst = blockIdx.x, tid = threadIdx.x;
  int start = indptr[dst];
  int deg = indptr[dst + 1] - start;
  __shared__ float md[2];
  __shared__ float al_sh[64];
  __shared__ int src_sh[64];
  int lane = tid & 63, wave = tid >> 6;

  if (wave == 0) {
    float ad = a_d[dst];
    float mx = -1e30f;
    for (int j = lane; j < deg; j += 64) {
      float ev = a_s[other[eidx[start + j]]] + ad;
      ev = ev > 0.f ? ev : NEG_SLOPE * ev;
      mx = fmaxf(mx, ev);
    }
#pragma unroll
    for (int off = 32; off; off >>= 1) mx = fmaxf(mx, __shfl_down(mx, off));
    mx = __shfl(mx, 0);
    float sm = 0.f;
    for (int j = lane; j < deg; j += 64) {
      float ev = a_s[other[eidx[start + j]]] + ad;
      ev = ev > 0.f ? ev : NEG_SLOPE * ev;
      sm += __expf(ev - mx);
    }
#pragma unroll
    for (int off = 32; off; off >>= 1) sm += __shfl_down(sm, off);
    if (lane == 0) { md[0] = mx; md[1] = sm + 1e-16f; }
  }
  __syncthreads();
  float mx = md[0], dn = md[1];
  float acc = 0.f;
  for (int base = 0; base < deg; base += 64) {
    int cnt = min(64, deg - base);
    if (tid < cnt) {
      int s = other[eidx[start + base + tid]];
      float ev = a_s[s] + a_d[dst];
      ev = ev > 0.f ? ev : NEG_SLOPE * ev;
      al_sh[tid] = __expf(ev - mx) / dn;
      src_sh[tid] = s;
    }
    __syncthreads();
    for (int j = 0; j < cnt; ++j)
      acc += al_sh[j] * h2[(size_t)src_sh[j] * 256 + tid];
    __syncthreads();
  }
  float v = acc + b2[tid];
  x3[(size_t)dst * 256 + tid] = fmaxf(v, 0.f);
}

// ---------------------------------------------------------------------------
extern "C" void kernel_launch(void* const* d_in, const int* in_sizes, int n_in,
                              void* d_out, int out_size, void* d_ws, size_t ws_size,
                              hipStream_t stream) {
  (void)n_in; (void)out_size; (void)ws_size;
  const float* constraints = (const float*)d_in[0];
  const float* columns     = (const float*)d_in[1];
  const void*  edges       = d_in[2];
  const float* W_node = (const float*)d_in[3];
  const float* b_node = (const float*)d_in[4];
  const float* W_col  = (const float*)d_in[5];
  const float* b_col  = (const float*)d_in[6];
  const float* W1       = (const float*)d_in[7];
  const float* att_src1 = (const float*)d_in[8];
  const float* att_dst1 = (const float*)d_in[9];
  const float* b1       = (const float*)d_in[10];
  const float* W2       = (const float*)d_in[11];
  const float* att_src2 = (const float*)d_in[12];
  const float* att_dst2 = (const float*)d_in[13];
  const float* b2       = (const float*)d_in[14];
  const float* W_out    = (const float*)d_in[15];
  const float* b_out    = (const float*)d_in[16];

  const int Nc   = in_sizes[0] / 64;
  const int Ncol = in_sizes[1] / 128;
  const int E    = in_sizes[2] / 2;
  const int N    = Nc + Ncol;
  const int E1   = E + N;

  char* p = (char*)d_ws;
  size_t off = 0;
  auto alloc = [&](size_t nbytes) -> void* {
    void* r = p + off;
    off = (off + nbytes + 255) & ~(size_t)255;
    return r;
  };
  float* Wn_f = (float*)alloc(sizeof(float) * 256 * 64);
  float* Wc_f = (float*)alloc(sizeof(float) * 256 * 128);
  float* x    = (float*)alloc(sizeof(float) * (size_t)N * 256);
  unsigned short* h1 = (unsigned short*)alloc(2ull * (size_t)N * 2048);
  float* a_s1 = (float*)alloc(sizeof(float) * (size_t)N * 8);
  float* a_d1 = (float*)alloc(sizeof(float) * (size_t)N * 8);
  int* esrc = (int*)alloc(4ull * E1);
  int* edst = (int*)alloc(4ull * E1);
  int* cnt1 = (int*)alloc(4ull * 2 * N);
  int* cnt2 = cnt1 + N;
  int* indptr1 = (int*)alloc(4ull * (N + 1));
  int* cur1    = (int*)alloc(4ull * N);
  int* indptr2 = (int*)alloc(4ull * (N + 1));
  int* cur2    = (int*)alloc(4ull * N);
  int* eidx1 = (int*)alloc(4ull * E1);
  int* eidx2 = (int*)alloc(4ull * E1);
  unsigned short* x2 = (unsigned short*)alloc(2ull * (size_t)N * 2048);
  float* h2   = (float*)alloc(sizeof(float) * (size_t)N * 256);
  float* a_s2 = (float*)alloc(sizeof(float) * (size_t)N);
  float* a_d2 = (float*)alloc(sizeof(float) * (size_t)N);
  float* x3   = (float*)alloc(sizeof(float) * (size_t)N * 256);

  hipMemsetAsync(cnt1, 0, 4ull * 2 * N, stream);
  fold_weights<<<192, 256, 0, stream>>>(W_node, W_col, Wn_f, Wc_f);

  // encoder
  gemm_bt<false, false, true, true><<<dim3(4, (Nc + 63) / 64), 256, 0, stream>>>(
      constraints, Wn_f, b_node, x, Nc, 64, 256);
  gemm_bt<false, false, true, true><<<dim3(4, (Ncol + 63) / 64), 256, 0, stream>>>(
      columns, Wc_f, b_col, x + (size_t)Nc * 256, Ncol, 128, 256);

  // conv1 projection + attention dots
  gemm_bt<false, true, false, false><<<dim3(32, (N + 63) / 64), 256, 0, stream>>>(
      x, W1, nullptr, h1, N, 256, 2048);
  att_dots<true><<<(N * 8 + 3) / 4, 256, 0, stream>>>(h1, att_src1, att_dst1, a_s1, a_d1, N, 8);

  // graph CSR (both directions)
  build_edges<<<(E1 + 255) / 256, 256, 0, stream>>>(edges, E, N, esrc, edst, E1);
  count_edges<<<(E1 + 255) / 256, 256, 0, stream>>>(esrc, edst, cnt1, cnt2, E1);
  scan2_kernel<<<1, 1024, 0, stream>>>(cnt1, indptr1, cur1, cnt2, indptr2, cur2, N);
  scatter_edges<<<(E1 + 255) / 256, 256, 0, stream>>>(esrc, edst, cur1, cur2, eidx1, eidx2, E1);

  // conv1 aggregate -> x2 (bf16), then conv2 projection
  conv1_agg<<<N, 256, 0, stream>>>(h1, a_s1, a_d1, esrc, indptr1, eidx1, b1, x2);
  gemm_bt<true, false, false, false><<<dim3(4, (N + 63) / 64), 256, 0, stream>>>(
      x2, W2, nullptr, h2, N, 2048, 256);
  att_dots<false><<<(N + 3) / 4, 256, 0, stream>>>(h2, att_src2, att_dst2, a_s2, a_d2, N, 1);
  conv2_agg<<<N, 256, 0, stream>>>(h2, a_s2, a_d2, edst, indptr2, eidx2, b2, x3);

  // output projection (rows Nc..N)
  gemm_bt<false, false, false, true><<<dim3(2, (Ncol + 63) / 64), 256, 0, stream>>>(
      x3 + (size_t)Nc * 256, W_out, b_out, (float*)d_out, Ncol, 256, 128);
}

// Round 2
// 550.888 us; speedup vs baseline: 2.2023x; 2.2023x over previous
//
#include <hip/hip_runtime.h>

// ---------------------------------------------------------------------------
// GAT 2-layer forward on MI355X. Round 2: bf16 MFMA for the two 21-GF GEMMs.
// ---------------------------------------------------------------------------

#define NEG_SLOPE 0.2f

typedef __attribute__((ext_vector_type(8))) short bf16x8;
typedef __attribute__((ext_vector_type(4))) float f32x4;

__device__ __forceinline__ float bf2f(unsigned short u) {
  return __uint_as_float(((unsigned)u) << 16);
}
__device__ __forceinline__ unsigned short f2bf(float f) {
  unsigned u = __float_as_uint(f);
  u += 0x7fffu + ((u >> 16) & 1u);   // round-to-nearest-even
  return (unsigned short)(u >> 16);
}

__device__ __forceinline__ void async_copy16(const void* g, void* l) {
  __builtin_amdgcn_global_load_lds(
      (const __attribute__((address_space(1))) unsigned int*)g,
      (__attribute__((address_space(3))) unsigned int*)l, 16, 0, 0);
}

// ---------------------------------------------------------------------------
// Fold W_node [256,128] -> Wn_f [256,64] (sum halves), W_col [256,256] -> [256,128]
__global__ void fold_weights(const float* __restrict__ Wn, const float* __restrict__ Wc,
                             float* __restrict__ Wn_f, float* __restrict__ Wc_f) {
  int idx = blockIdx.x * 256 + threadIdx.x;
  if (idx < 256 * 64) {
    int o = idx >> 6, j = idx & 63;
    Wn_f[idx] = Wn[o * 128 + j] + Wn[o * 128 + 64 + j];
  }
  idx -= 256 * 64;
  if (idx >= 0 && idx < 256 * 128) {
    int o = idx >> 7, j = idx & 127;
    Wc_f[idx] = Wc[o * 256 + j] + Wc[o * 256 + 128 + j];
  }
}

// f32 -> bf16 conversion (grid-stride), used for W1 and W2.
__global__ void f32_to_bf16(const float* __restrict__ in, unsigned short* __restrict__ out,
                            int n) {
  for (int i = blockIdx.x * 256 + threadIdx.x; i < n; i += gridDim.x * 256)
    out[i] = f2bf(in[i]);
}

// ---------------------------------------------------------------------------
// f32 VALU tiled GEMM (small GEMMs only), B^T layout: C[m,n]=sum_k A[m,k]W[n,k]
template <bool A_BF16, bool C_BF16, bool RELU, bool BIAS>
__global__ __launch_bounds__(256) void gemm_bt(const void* __restrict__ Av,
                                               const float* __restrict__ W,
                                               const float* __restrict__ bias,
                                               void* __restrict__ Cv,
                                               int M, int K, int Nout) {
  const float* Af = (const float*)Av;
  const unsigned short* Ab = (const unsigned short*)Av;
  float* Cf = (float*)Cv;
  unsigned short* Cb = (unsigned short*)Cv;

  __shared__ float As[16][65];
  __shared__ float Bs[16][65];

  int tid = threadIdx.x;
  int m0 = blockIdx.y * 64, n0 = blockIdx.x * 64;
  int tx = tid & 15, ty = tid >> 4;
  float acc[4][4] = {};

  for (int k0 = 0; k0 < K; k0 += 16) {
#pragma unroll
    for (int l = 0; l < 4; ++l) {
      int idx = tid + l * 256;
      int ar = idx >> 4, ac = idx & 15;
      int row = m0 + ar;
      float v = 0.f;
      if (row < M) {
        size_t a = (size_t)row * K + k0 + ac;
        v = A_BF16 ? bf2f(Ab[a]) : Af[a];
      }
      As[ac][ar] = v;
    }
#pragma unroll
    for (int l = 0; l < 4; ++l) {
      int idx = tid + l * 256;
      int nr = idx >> 4, kc = idx & 15;
      Bs[kc][nr] = W[(size_t)(n0 + nr) * K + k0 + kc];
    }
    __syncthreads();
#pragma unroll
    for (int kk = 0; kk < 16; ++kk) {
      float a[4], b[4];
#pragma unroll
      for (int i = 0; i < 4; ++i) a[i] = As[kk][ty + 16 * i];
#pragma unroll
      for (int j = 0; j < 4; ++j) b[j] = Bs[kk][tx + 16 * j];
#pragma unroll
      for (int i = 0; i < 4; ++i)
#pragma unroll
        for (int j = 0; j < 4; ++j) acc[i][j] += a[i] * b[j];
    }
    __syncthreads();
  }

#pragma unroll
  for (int i = 0; i < 4; ++i) {
    int row = m0 + ty + 16 * i;
    if (row >= M) continue;
#pragma unroll
    for (int j = 0; j < 4; ++j) {
      int col = n0 + tx + 16 * j;
      float v = acc[i][j];
      if (BIAS) v += bias[col];
      if (RELU) v = fmaxf(v, 0.f);
      size_t o = (size_t)row * Nout + col;
      if (C_BF16) Cb[o] = f2bf(v); else Cf[o] = v;
    }
  }
}

// ---------------------------------------------------------------------------
// bf16 MFMA GEMM, B^T layout: C[m,n] = sum_k A[m,k] * W[n,k].
// A: [M,K] bf16 row-major. W: [Nout,K] bf16 row-major. Tile 128x128, BK=64,
// 256 threads = 4 waves in 2x2; each wave 4x4 frags of 16x16 via
// mfma_f32_16x16x32_bf16. global_load_lds width=16 staging (m97 pattern).
// Requires: K % 64 == 0, Nout % 128 == 0.
template <bool C_BF16>
__global__ __launch_bounds__(256) void gemm_mfma_bt(const unsigned short* __restrict__ A,
                                                    const unsigned short* __restrict__ W,
                                                    void* __restrict__ Cv,
                                                    int M, int K, int Nout) {
  __shared__ short sA[128 * 64];
  __shared__ short sB[128 * 64];
  float* Cf = (float*)Cv;
  unsigned short* Cb = (unsigned short*)Cv;

  const int tid = threadIdx.x;
  const int lane = tid & 63, w = tid >> 6;
  const int m0 = blockIdx.y * 128, n0 = blockIdx.x * 128;
  const int wm = (w >> 1) * 64, wn = (w & 1) * 64;
  const int fr = lane & 15;        // fragment row (m for A, n for B)
  const int quad = lane >> 4;      // k-offset quad*8

  f32x4 acc[4][4];
#pragma unroll
  for (int i = 0; i < 4; ++i)
#pragma unroll
    for (int j = 0; j < 4; ++j) acc[i][j] = (f32x4){0.f, 0.f, 0.f, 0.f};

  for (int k0 = 0; k0 < K; k0 += 64) {
    // stage A tile: 128 rows x 64 cols bf16 = 1024 16B-chunks
#pragma unroll
    for (int i = 0; i < 4; ++i) {
      int c = i * 256 + tid;          // chunk id
      int row = c >> 3, kc = c & 7;
      int grow = m0 + row;
      if (grow >= M) grow = M - 1;    // clamp (stores are guarded)
      async_copy16(A + (size_t)grow * K + k0 + kc * 8,
                   &sA[(i * 256 + w * 64) * 8]);
    }
    // stage B tile: 128 n-rows x 64 cols
#pragma unroll
    for (int i = 0; i < 4; ++i) {
      int c = i * 256 + tid;
      int row = c >> 3, kc = c & 7;
      async_copy16(W + (size_t)(n0 + row) * K + k0 + kc * 8,
                   &sB[(i * 256 + w * 64) * 8]);
    }
    __syncthreads();

#pragma unroll
    for (int ks = 0; ks < 2; ++ks) {
      bf16x8 af[4], bfr[4];
#pragma unroll
      for (int mi = 0; mi < 4; ++mi)
        af[mi] = *(const bf16x8*)&sA[(wm + mi * 16 + fr) * 64 + ks * 32 + quad * 8];
#pragma unroll
      for (int ni = 0; ni < 4; ++ni)
        bfr[ni] = *(const bf16x8*)&sB[(wn + ni * 16 + fr) * 64 + ks * 32 + quad * 8];
#pragma unroll
      for (int mi = 0; mi < 4; ++mi)
#pragma unroll
        for (int ni = 0; ni < 4; ++ni)
          acc[mi][ni] = __builtin_amdgcn_mfma_f32_16x16x32_bf16(
              af[mi], bfr[ni], acc[mi][ni], 0, 0, 0);
    }
    __syncthreads();
  }

  // epilogue: C/D layout col=lane&15, row=quad*4+reg
#pragma unroll
  for (int mi = 0; mi < 4; ++mi) {
#pragma unroll
    for (int ni = 0; ni < 4; ++ni) {
      int col = n0 + wn + ni * 16 + fr;
      f32x4 v = acc[mi][ni];
#pragma unroll
      for (int r = 0; r < 4; ++r) {
        int row = m0 + wm + mi * 16 + quad * 4 + r;
        if (row < M) {
          size_t o = (size_t)row * Nout + col;
          if (C_BF16) Cb[o] = f2bf(v[r]); else Cf[o] = v[r];
        }
      }
    }
  }
}

// ---------------------------------------------------------------------------
// a_s[n,h] = dot(h[n,h,:], att_s[h,:]); a_d likewise. One wave per (n,h), C=256.
template <bool BF16>
__global__ __launch_bounds__(256) void att_dots(const void* __restrict__ hv,
                                                const float* __restrict__ att_s,
                                                const float* __restrict__ att_d,
                                                float* __restrict__ a_s,
                                                float* __restrict__ a_d,
                                                int N, int H) {
  int wid = (blockIdx.x * 256 + threadIdx.x) >> 6;
  int lane = threadIdx.x & 63;
  if (wid >= N * H) return;
  int n = wid / H, hh = wid - n * H;
  int c = lane * 4;
  float v[4];
  if (BF16) {
    const unsigned short* row = (const unsigned short*)hv + (size_t)n * H * 256 + hh * 256;
    ushort4 r = *(const ushort4*)(row + c);
    v[0] = bf2f(r.x); v[1] = bf2f(r.y); v[2] = bf2f(r.z); v[3] = bf2f(r.w);
  } else {
    const float* row = (const float*)hv + (size_t)n * H * 256 + hh * 256;
    float4 r = *(const float4*)(row + c);
    v[0] = r.x; v[1] = r.y; v[2] = r.z; v[3] = r.w;
  }
  float4 sa = *(const float4*)(att_s + hh * 256 + c);
  float4 da = *(const float4*)(att_d + hh * 256 + c);
  float s1 = v[0] * sa.x + v[1] * sa.y + v[2] * sa.z + v[3] * sa.w;
  float s2 = v[0] * da.x + v[1] * da.y + v[2] * da.z + v[3] * da.w;
#pragma unroll
  for (int off = 32; off; off >>= 1) {
    s1 += __shfl_down(s1, off);
    s2 += __shfl_down(s2, off);
  }
  if (lane == 0) { a_s[wid] = s1; a_d[wid] = s2; }
}

// ---------------------------------------------------------------------------
// Edge materialization: int64-vs-int32 auto-detect, append self loops.
__global__ void build_edges(const void* __restrict__ edges_raw, int E, int N,
                            int* __restrict__ esrc, int* __restrict__ edst, int E1) {
  const long long* p64 = (const long long*)edges_raw;
  const int* p32 = (const int*)edges_raw;
  bool is64 = true;
#pragma unroll
  for (int i = 0; i < 8; ++i) {
    long long v = p64[i];
    if (v < 0 || v >= N) is64 = false;
  }
  int idx = blockIdx.x * 256 + threadIdx.x;
  if (idx >= E1) return;
  if (idx < E) {
    long long s, d;
    if (is64) { s = p64[idx]; d = p64[E + idx]; }
    else      { s = p32[idx]; d = p32[E + idx]; }
    esrc[idx] = (int)s;
    edst[idx] = (int)d;
  } else {
    int n = idx - E;
    esrc[idx] = n;
    edst[idx] = n;
  }
}

__global__ void count_edges(const int* __restrict__ esrc, const int* __restrict__ edst,
                            int* __restrict__ cnt1, int* __restrict__ cnt2, int E1) {
  int e = blockIdx.x * 256 + threadIdx.x;
  if (e >= E1) return;
  atomicAdd(&cnt1[edst[e]], 1);
  atomicAdd(&cnt2[esrc[e]], 1);
}

__device__ void scan_one(const int* __restrict__ cnt, int* __restrict__ indptr,
                         int* __restrict__ cur, int N, int* buf) {
  int t = threadIdx.x;
  int running = 0;
  for (int base = 0; base < N; base += 1024) {
    int v = (base + t < N) ? cnt[base + t] : 0;
    buf[t] = v;
    __syncthreads();
    for (int off = 1; off < 1024; off <<= 1) {
      int x = (t >= off) ? buf[t - off] : 0;
      __syncthreads();
      buf[t] += x;
      __syncthreads();
    }
    int incl = buf[t];
    if (base + t < N) {
      int excl = running + incl - v;
      indptr[base + t] = excl;
      cur[base + t] = excl;
    }
    int tot = buf[1023];
    __syncthreads();
    running += tot;
  }
  if (t == 0) indptr[N] = running;
  __syncthreads();
}

__global__ __launch_bounds__(1024) void scan2_kernel(const int* cnt1, int* indptr1, int* cur1,
                                                     const int* cnt2, int* indptr2, int* cur2,
                                                     int N) {
  __shared__ int buf[1024];
  scan_one(cnt1, indptr1, cur1, N, buf);
  scan_one(cnt2, indptr2, cur2, N, buf);
}

__global__ void scatter_edges(const int* __restrict__ esrc, const int* __restrict__ edst,
                              int* __restrict__ cur1, int* __restrict__ cur2,
                              int* __restrict__ eidx1, int* __restrict__ eidx2, int E1) {
  int e = blockIdx.x * 256 + threadIdx.x;
  if (e >= E1) return;
  int p1 = atomicAdd(&cur1[edst[e]], 1);
  eidx1[p1] = e;
  int p2 = atomicAdd(&cur2[esrc[e]], 1);
  eidx2[p2] = e;
}

// ---------------------------------------------------------------------------
// conv1: per-dst softmax (8 heads) + weighted aggregation of h1[src] (bf16 2048-wide).
__global__ __launch_bounds__(256) void conv1_agg(const unsigned short* __restrict__ h1,
                                                 const float* __restrict__ a_s,
                                                 const float* __restrict__ a_d,
                                                 const int* __restrict__ esrc,
                                                 const int* __restrict__ indptr,
                                                 const int* __restrict__ eidx,
                                                 const float* __restrict__ b1,
                                                 unsigned short* __restrict__ x2) {
  int dst = blockIdx.x, tid = threadIdx.x;
  int start = indptr[dst];
  int deg = indptr[dst + 1] - start;
  __shared__ float m_sh[8], d_sh[8];
  __shared__ float al_sh[64 * 8];
  __shared__ int src_sh[64];
  int lane = tid & 63, wave = tid >> 6;

  for (int h = wave; h < 8; h += 4) {
    float ad = a_d[dst * 8 + h];
    float mx = -1e30f;
    for (int j = lane; j < deg; j += 64) {
      int e = eidx[start + j];
      float ev = a_s[esrc[e] * 8 + h] + ad;
      ev = ev > 0.f ? ev : NEG_SLOPE * ev;
      mx = fmaxf(mx, ev);
    }
#pragma unroll
    for (int off = 32; off; off >>= 1) mx = fmaxf(mx, __shfl_down(mx, off));
    mx = __shfl(mx, 0);
    float sm = 0.f;
    for (int j = lane; j < deg; j += 64) {
      int e = eidx[start + j];
      float ev = a_s[esrc[e] * 8 + h] + ad;
      ev = ev > 0.f ? ev : NEG_SLOPE * ev;
      sm += __expf(ev - mx);
    }
#pragma unroll
    for (int off = 32; off; off >>= 1) sm += __shfl_down(sm, off);
    if (lane == 0) { m_sh[h] = mx; d_sh[h] = sm + 1e-16f; }
  }
  __syncthreads();

  float acc[8] = {0.f, 0.f, 0.f, 0.f, 0.f, 0.f, 0.f, 0.f};
  int myhead = tid >> 5;
  for (int base = 0; base < deg; base += 64) {
    int cnt = min(64, deg - base);
    for (int t = tid; t < cnt * 8; t += 256) {
      int j = t >> 3, h = t & 7;
      int e = eidx[start + base + j];
      int s = esrc[e];
      if (h == 0) src_sh[j] = s;
      float ev = a_s[s * 8 + h] + a_d[dst * 8 + h];
      ev = ev > 0.f ? ev : NEG_SLOPE * ev;
      al_sh[j * 8 + h] = __expf(ev - m_sh[h]) / d_sh[h];
    }
    __syncthreads();
    for (int j = 0; j < cnt; ++j) {
      float al = al_sh[j * 8 + myhead];
      const float4* hp = (const float4*)(h1 + (size_t)src_sh[j] * 2048);
      float4 r = hp[tid];
      const unsigned short* rb = (const unsigned short*)&r;
#pragma unroll
      for (int i = 0; i < 8; ++i) acc[i] += al * bf2f(rb[i]);
    }
    __syncthreads();
  }

  unsigned short outv[8];
#pragma unroll
  for (int i = 0; i < 8; ++i) {
    float v = acc[i] + b1[tid * 8 + i];
    outv[i] = f2bf(fmaxf(v, 0.f));
  }
  *((float4*)(x2 + (size_t)dst * 2048 + tid * 8)) = *((const float4*)outv);
}

// ---------------------------------------------------------------------------
// conv2: 1 head, 256-wide f32. One block per dst; thread t owns channel t.
__global__ __launch_bounds__(256) void conv2_agg(const float* __restrict__ h2,
                                                 const float* __restrict__ a_s,
                                                 const float* __restrict__ a_d,
                                                 const int* __restrict__ other,
                                                 const int* __restrict__ indptr,
                                                 const int* __restrict__ eidx,
                                                 const float* __restrict__ b2,
                                                 float* __restrict__ x3) {
  int dst = blockIdx.x, tid = threadIdx.x;
  int start = indptr[dst];
  int deg = indptr[dst + 1] - start;
  __shared__ float md[2];
  __shared__ float al_sh[64];
  __shared__ int src_sh[64];
  int lane = tid & 63, wave = tid >> 6;

  if (wave == 0) {
    float ad = a_d[dst];
    float mx = -1e30f;
    for (int j = lane; j < deg; j += 64) {
      float ev = a_s[other[eidx[start + j]]] + ad;
      ev = ev > 0.f ? ev : NEG_SLOPE * ev;
      mx = fmaxf(mx, ev);
    }
#pragma unroll
    for (int off = 32; off; off >>= 1) mx = fmaxf(mx, __shfl_down(mx, off));
    mx = __shfl(mx, 0);
    float sm = 0.f;
    for (int j = lane; j < deg; j += 64) {
      float ev = a_s[other[eidx[start + j]]] + ad;
      ev = ev > 0.f ? ev : NEG_SLOPE * ev;
      sm += __expf(ev - mx);
    }
#pragma unroll
    for (int off = 32; off; off >>= 1) sm += __shfl_down(sm, off);
    if (lane == 0) { md[0] = mx; md[1] = sm + 1e-16f; }
  }
  __syncthreads();
  float mx = md[0], dn = md[1];
  float acc = 0.f;
  for (int base = 0; base < deg; base += 64) {
    int cnt = min(64, deg - base);
    if (tid < cnt) {
      int s = other[eidx[start + base + tid]];
      float ev = a_s[s] + a_d[dst];
      ev = ev > 0.f ? ev : NEG_SLOPE * ev;
      al_sh[tid] = __expf(ev - mx) / dn;
      src_sh[tid] = s;
    }
    __syncthreads();
    for (int j = 0; j < cnt; ++j)
      acc += al_sh[j] * h2[(size_t)src_sh[j] * 256 + tid];
    __syncthreads();
  }
  float v = acc + b2[tid];
  x3[(size_t)dst * 256 + tid] = fmaxf(v, 0.f);
}

// ---------------------------------------------------------------------------
extern "C" void kernel_launch(void* const* d_in, const int* in_sizes, int n_in,
                              void* d_out, int out_size, void* d_ws, size_t ws_size,
                              hipStream_t stream) {
  (void)n_in; (void)out_size; (void)ws_size;
  const float* constraints = (const float*)d_in[0];
  const float* columns     = (const float*)d_in[1];
  const void*  edges       = d_in[2];
  const float* W_node = (const float*)d_in[3];
  const float* b_node = (const float*)d_in[4];
  const float* W_col  = (const float*)d_in[5];
  const float* b_col  = (const float*)d_in[6];
  const float* W1       = (const float*)d_in[7];
  const float* att_src1 = (const float*)d_in[8];
  const float* att_dst1 = (const float*)d_in[9];
  const float* b1       = (const float*)d_in[10];
  const float* W2       = (const float*)d_in[11];
  const float* att_src2 = (const float*)d_in[12];
  const float* att_dst2 = (const float*)d_in[13];
  const float* b2       = (const float*)d_in[14];
  const float* W_out    = (const float*)d_in[15];
  const float* b_out    = (const float*)d_in[16];

  const int Nc   = in_sizes[0] / 64;
  const int Ncol = in_sizes[1] / 128;
  const int E    = in_sizes[2] / 2;
  const int N    = Nc + Ncol;
  const int E1   = E + N;

  char* p = (char*)d_ws;
  size_t off = 0;
  auto alloc = [&](size_t nbytes) -> void* {
    void* r = p + off;
    off = (off + nbytes + 255) & ~(size_t)255;
    return r;
  };
  float* Wn_f = (float*)alloc(sizeof(float) * 256 * 64);
  float* Wc_f = (float*)alloc(sizeof(float) * 256 * 128);
  unsigned short* xb   = (unsigned short*)alloc(2ull * (size_t)N * 256);
  unsigned short* W1b  = (unsigned short*)alloc(2ull * 2048 * 256);
  unsigned short* W2b  = (unsigned short*)alloc(2ull * 256 * 2048);
  unsigned short* h1 = (unsigned short*)alloc(2ull * (size_t)N * 2048);
  float* a_s1 = (float*)alloc(sizeof(float) * (size_t)N * 8);
  float* a_d1 = (float*)alloc(sizeof(float) * (size_t)N * 8);
  int* esrc = (int*)alloc(4ull * E1);
  int* edst = (int*)alloc(4ull * E1);
  int* cnt1 = (int*)alloc(4ull * 2 * N);
  int* cnt2 = cnt1 + N;
  int* indptr1 = (int*)alloc(4ull * (N + 1));
  int* cur1    = (int*)alloc(4ull * N);
  int* indptr2 = (int*)alloc(4ull * (N + 1));
  int* cur2    = (int*)alloc(4ull * N);
  int* eidx1 = (int*)alloc(4ull * E1);
  int* eidx2 = (int*)alloc(4ull * E1);
  unsigned short* x2 = (unsigned short*)alloc(2ull * (size_t)N * 2048);
  float* h2   = (float*)alloc(sizeof(float) * (size_t)N * 256);
  float* a_s2 = (float*)alloc(sizeof(float) * (size_t)N);
  float* a_d2 = (float*)alloc(sizeof(float) * (size_t)N);
  float* x3   = (float*)alloc(sizeof(float) * (size_t)N * 256);

  hipMemsetAsync(cnt1, 0, 4ull * 2 * N, stream);
  fold_weights<<<192, 256, 0, stream>>>(W_node, W_col, Wn_f, Wc_f);
  f32_to_bf16<<<512, 256, 0, stream>>>(W1, W1b, 2048 * 256);
  f32_to_bf16<<<512, 256, 0, stream>>>(W2, W2b, 256 * 2048);

  // encoder (writes x directly as bf16 for the MFMA GEMM)
  gemm_bt<false, true, true, true><<<dim3(4, (Nc + 63) / 64), 256, 0, stream>>>(
      constraints, Wn_f, b_node, xb, Nc, 64, 256);
  gemm_bt<false, true, true, true><<<dim3(4, (Ncol + 63) / 64), 256, 0, stream>>>(
      columns, Wc_f, b_col, xb + (size_t)Nc * 256, Ncol, 128, 256);

  // conv1 projection (MFMA) + attention dots
  gemm_mfma_bt<true><<<dim3(16, (N + 127) / 128), 256, 0, stream>>>(
      xb, W1b, h1, N, 256, 2048);
  att_dots<true><<<(N * 8 + 3) / 4, 256, 0, stream>>>(h1, att_src1, att_dst1, a_s1, a_d1, N, 8);

  // graph CSR (both directions)
  build_edges<<<(E1 + 255) / 256, 256, 0, stream>>>(edges, E, N, esrc, edst, E1);
  count_edges<<<(E1 + 255) / 256, 256, 0, stream>>>(esrc, edst, cnt1, cnt2, E1);
  scan2_kernel<<<1, 1024, 0, stream>>>(cnt1, indptr1, cur1, cnt2, indptr2, cur2, N);
  scatter_edges<<<(E1 + 255) / 256, 256, 0, stream>>>(esrc, edst, cur1, cur2, eidx1, eidx2, E1);

  // conv1 aggregate -> x2 (bf16), then conv2 projection (MFMA)
  conv1_agg<<<N, 256, 0, stream>>>(h1, a_s1, a_d1, esrc, indptr1, eidx1, b1, x2);
  gemm_mfma_bt<false><<<dim3(2, (N + 127) / 128), 256, 0, stream>>>(
      x2, W2b, h2, N, 2048, 256);
  att_dots<false><<<(N + 3) / 4, 256, 0, stream>>>(h2, att_src2, att_dst2, a_s2, a_d2, N, 1);
  conv2_agg<<<N, 256, 0, stream>>>(h2, a_s2, a_d2, edst, indptr2, eidx2, b2, x3);

  // output projection (rows Nc..N)
  gemm_bt<false, false, false, true><<<dim3(2, (Ncol + 63) / 64), 256, 0, stream>>>(
      x3 + (size_t)Nc * 256, W_out, b_out, (float*)d_out, Ncol, 256, 128);
}

// Round 3
// 475.410 us; speedup vs baseline: 2.5519x; 1.1588x over previous
//
#include <hip/hip_runtime.h>

// ---------------------------------------------------------------------------
// GAT 2-layer forward on MI355X. Round 3:
//  - shuffle-based scan (was ~1200 block barriers on 1 CU)
//  - conv2 GEMM: dedicated 32x256-tile kernel (A read once, 625 blocks)
//  - encoders/out-proj moved to MFMA (single fused f32->bf16 prep kernel)
//  - conv1_agg gather unrolled x4 for memory-level parallelism
// ---------------------------------------------------------------------------

#define NEG_SLOPE 0.2f

typedef __attribute__((ext_vector_type(8))) short bf16x8;
typedef __attribute__((ext_vector_type(4))) float f32x4;

__device__ __forceinline__ float bf2f(unsigned short u) {
  return __uint_as_float(((unsigned)u) << 16);
}
__device__ __forceinline__ unsigned short f2bf(float f) {
  unsigned u = __float_as_uint(f);
  u += 0x7fffu + ((u >> 16) & 1u);   // round-to-nearest-even
  return (unsigned short)(u >> 16);
}

__device__ __forceinline__ void async_copy16(const void* g, void* l) {
  __builtin_amdgcn_global_load_lds(
      (const __attribute__((address_space(1))) unsigned int*)g,
      (__attribute__((address_space(3))) unsigned int*)l, 16, 0, 0);
}

// ---------------------------------------------------------------------------
// prep: fold W_node/W_col halves (tile(x,2) folded into weights) + convert all
// MFMA operands to bf16 in one grid-stride kernel.
__global__ void prep(const float* __restrict__ Wn, const float* __restrict__ Wc,
                     const float* __restrict__ W1, const float* __restrict__ W2,
                     const float* __restrict__ Wout,
                     const float* __restrict__ cons, const float* __restrict__ cols,
                     unsigned short* __restrict__ Wn_b, unsigned short* __restrict__ Wc_b,
                     unsigned short* __restrict__ W1b, unsigned short* __restrict__ W2b,
                     unsigned short* __restrict__ Woutb,
                     unsigned short* __restrict__ consb, unsigned short* __restrict__ colsb,
                     int n_cons, int n_cols) {
  const int S0 = 256 * 64;      // Wn fold
  const int S1 = 256 * 128;     // Wc fold
  const int S2 = 2048 * 256;    // W1
  const int S3 = 256 * 2048;    // W2
  const int S4 = 128 * 256;     // Wout
  int total = S0 + S1 + S2 + S3 + S4 + n_cons + n_cols;
  for (int idx = blockIdx.x * 256 + threadIdx.x; idx < total; idx += gridDim.x * 256) {
    int i = idx;
    if (i < S0) { int o = i >> 6, j = i & 63;
      Wn_b[i] = f2bf(Wn[o * 128 + j] + Wn[o * 128 + 64 + j]); continue; }
    i -= S0;
    if (i < S1) { int o = i >> 7, j = i & 127;
      Wc_b[i] = f2bf(Wc[o * 256 + j] + Wc[o * 256 + 128 + j]); continue; }
    i -= S1;
    if (i < S2) { W1b[i] = f2bf(W1[i]); continue; }
    i -= S2;
    if (i < S3) { W2b[i] = f2bf(W2[i]); continue; }
    i -= S3;
    if (i < S4) { Woutb[i] = f2bf(Wout[i]); continue; }
    i -= S4;
    if (i < n_cons) { consb[i] = f2bf(cons[i]); continue; }
    i -= n_cons;
    colsb[i] = f2bf(cols[i]);
  }
}

// ---------------------------------------------------------------------------
// bf16 MFMA GEMM, B^T layout: C[m,n] = sum_k A[m,k] * W[n,k] (+bias, relu).
// Tile 128x128, BK=64, 256 thr (2x2 waves, 4x4 16x16 frags each).
// Requires K % 64 == 0, Nout % 128 == 0, grid.x == Nout/128.
template <bool C_BF16, bool BIAS, bool RELU>
__global__ __launch_bounds__(256) void gemm_mfma_bt(const unsigned short* __restrict__ A,
                                                    const unsigned short* __restrict__ W,
                                                    const float* __restrict__ bias,
                                                    void* __restrict__ Cv,
                                                    int M, int K, int Nout) {
  __shared__ short sA[128 * 64];
  __shared__ short sB[128 * 64];
  float* Cf = (float*)Cv;
  unsigned short* Cb = (unsigned short*)Cv;

  const int tid = threadIdx.x;
  const int lane = tid & 63, w = tid >> 6;
  const int m0 = blockIdx.y * 128, n0 = blockIdx.x * 128;
  const int wm = (w >> 1) * 64, wn = (w & 1) * 64;
  const int fr = lane & 15;
  const int quad = lane >> 4;

  f32x4 acc[4][4];
#pragma unroll
  for (int i = 0; i < 4; ++i)
#pragma unroll
    for (int j = 0; j < 4; ++j) acc[i][j] = (f32x4){0.f, 0.f, 0.f, 0.f};

  for (int k0 = 0; k0 < K; k0 += 64) {
#pragma unroll
    for (int i = 0; i < 4; ++i) {
      int c = i * 256 + tid;
      int row = c >> 3, kc = c & 7;
      int grow = m0 + row;
      if (grow >= M) grow = M - 1;
      async_copy16(A + (size_t)grow * K + k0 + kc * 8, &sA[(i * 256 + w * 64) * 8]);
    }
#pragma unroll
    for (int i = 0; i < 4; ++i) {
      int c = i * 256 + tid;
      int row = c >> 3, kc = c & 7;
      async_copy16(W + (size_t)(n0 + row) * K + k0 + kc * 8, &sB[(i * 256 + w * 64) * 8]);
    }
    __syncthreads();

#pragma unroll
    for (int ks = 0; ks < 2; ++ks) {
      bf16x8 af[4], bfr[4];
#pragma unroll
      for (int mi = 0; mi < 4; ++mi)
        af[mi] = *(const bf16x8*)&sA[(wm + mi * 16 + fr) * 64 + ks * 32 + quad * 8];
#pragma unroll
      for (int ni = 0; ni < 4; ++ni)
        bfr[ni] = *(const bf16x8*)&sB[(wn + ni * 16 + fr) * 64 + ks * 32 + quad * 8];
#pragma unroll
      for (int mi = 0; mi < 4; ++mi)
#pragma unroll
        for (int ni = 0; ni < 4; ++ni)
          acc[mi][ni] = __builtin_amdgcn_mfma_f32_16x16x32_bf16(
              af[mi], bfr[ni], acc[mi][ni], 0, 0, 0);
    }
    __syncthreads();
  }

#pragma unroll
  for (int mi = 0; mi < 4; ++mi) {
#pragma unroll
    for (int ni = 0; ni < 4; ++ni) {
      int col = n0 + wn + ni * 16 + fr;
      float bv = BIAS ? bias[col] : 0.f;
      f32x4 v = acc[mi][ni];
#pragma unroll
      for (int r = 0; r < 4; ++r) {
        int row = m0 + wm + mi * 16 + quad * 4 + r;
        if (row < M) {
          float x = v[r] + bv;
          if (RELU) x = fmaxf(x, 0.f);
          size_t o = (size_t)row * Nout + col;
          if (C_BF16) Cb[o] = f2bf(x); else Cf[o] = x;
        }
      }
    }
  }
}

// ---------------------------------------------------------------------------
// conv2 projection GEMM: C[M,256] = A[M,K=2048] * W[256,K]^T, f32 out.
// Tile 32 rows x 256 cols (full Nout) so A is read exactly once; grid = M/32
// blocks (625) for real occupancy. 4 waves: wave w owns cols [64w, 64w+64).
__global__ __launch_bounds__(256) void gemm_mfma_k2048(const unsigned short* __restrict__ A,
                                                       const unsigned short* __restrict__ W,
                                                       float* __restrict__ C,
                                                       int M, int K) {
  __shared__ short sA[32 * 64];
  __shared__ short sB[256 * 64];
  const int tid = threadIdx.x;
  const int lane = tid & 63, w = tid >> 6;
  const int m0 = blockIdx.x * 32;
  const int fr = lane & 15, quad = lane >> 4;

  f32x4 acc[2][4];
#pragma unroll
  for (int i = 0; i < 2; ++i)
#pragma unroll
    for (int j = 0; j < 4; ++j) acc[i][j] = (f32x4){0.f, 0.f, 0.f, 0.f};

  for (int k0 = 0; k0 < K; k0 += 64) {
    { // A tile: 32 rows x 64 cols = 256 16B chunks, 1/thread
      int row = tid >> 3, kc = tid & 7;
      int grow = m0 + row;
      if (grow >= M) grow = M - 1;
      async_copy16(A + (size_t)grow * K + k0 + kc * 8, &sA[(w * 64) * 8]);
    }
#pragma unroll
    for (int i = 0; i < 8; ++i) { // B tile: 256 rows x 64 cols
      int c = i * 256 + tid;
      int row = c >> 3, kc = c & 7;
      async_copy16(W + (size_t)row * K + k0 + kc * 8, &sB[(i * 256 + w * 64) * 8]);
    }
    __syncthreads();

#pragma unroll
    for (int ks = 0; ks < 2; ++ks) {
      bf16x8 af[2], bfr[4];
#pragma unroll
      for (int mi = 0; mi < 2; ++mi)
        af[mi] = *(const bf16x8*)&sA[(mi * 16 + fr) * 64 + ks * 32 + quad * 8];
#pragma unroll
      for (int ni = 0; ni < 4; ++ni)
        bfr[ni] = *(const bf16x8*)&sB[(w * 64 + ni * 16 + fr) * 64 + ks * 32 + quad * 8];
#pragma unroll
      for (int mi = 0; mi < 2; ++mi)
#pragma unroll
        for (int ni = 0; ni < 4; ++ni)
          acc[mi][ni] = __builtin_amdgcn_mfma_f32_16x16x32_bf16(
              af[mi], bfr[ni], acc[mi][ni], 0, 0, 0);
    }
    __syncthreads();
  }

#pragma unroll
  for (int mi = 0; mi < 2; ++mi)
#pragma unroll
    for (int ni = 0; ni < 4; ++ni) {
      int col = w * 64 + ni * 16 + fr;
      f32x4 v = acc[mi][ni];
#pragma unroll
      for (int r = 0; r < 4; ++r) {
        int row = m0 + mi * 16 + quad * 4 + r;
        if (row < M) C[(size_t)row * 256 + col] = v[r];
      }
    }
}

// ---------------------------------------------------------------------------
// a_s[n,h] = dot(h[n,h,:], att_s[h,:]); a_d likewise. One wave per (n,h), C=256.
template <bool BF16>
__global__ __launch_bounds__(256) void att_dots(const void* __restrict__ hv,
                                                const float* __restrict__ att_s,
                                                const float* __restrict__ att_d,
                                                float* __restrict__ a_s,
                                                float* __restrict__ a_d,
                                                int N, int H) {
  int wid = (blockIdx.x * 256 + threadIdx.x) >> 6;
  int lane = threadIdx.x & 63;
  if (wid >= N * H) return;
  int n = wid / H, hh = wid - n * H;
  int c = lane * 4;
  float v[4];
  if (BF16) {
    const unsigned short* row = (const unsigned short*)hv + (size_t)n * H * 256 + hh * 256;
    ushort4 r = *(const ushort4*)(row + c);
    v[0] = bf2f(r.x); v[1] = bf2f(r.y); v[2] = bf2f(r.z); v[3] = bf2f(r.w);
  } else {
    const float* row = (const float*)hv + (size_t)n * H * 256 + hh * 256;
    float4 r = *(const float4*)(row + c);
    v[0] = r.x; v[1] = r.y; v[2] = r.z; v[3] = r.w;
  }
  float4 sa = *(const float4*)(att_s + hh * 256 + c);
  float4 da = *(const float4*)(att_d + hh * 256 + c);
  float s1 = v[0] * sa.x + v[1] * sa.y + v[2] * sa.z + v[3] * sa.w;
  float s2 = v[0] * da.x + v[1] * da.y + v[2] * da.z + v[3] * da.w;
#pragma unroll
  for (int off = 32; off; off >>= 1) {
    s1 += __shfl_down(s1, off);
    s2 += __shfl_down(s2, off);
  }
  if (lane == 0) { a_s[wid] = s1; a_d[wid] = s2; }
}

// ---------------------------------------------------------------------------
// Edge materialization + degree counts (fused). int64/int32 auto-detect.
__global__ void build_count(const void* __restrict__ edges_raw, int E, int N,
                            int* __restrict__ esrc, int* __restrict__ edst,
                            int* __restrict__ cnt1, int* __restrict__ cnt2, int E1) {
  const long long* p64 = (const long long*)edges_raw;
  const int* p32 = (const int*)edges_raw;
  bool is64 = true;
#pragma unroll
  for (int i = 0; i < 8; ++i) {
    long long v = p64[i];
    if (v < 0 || v >= N) is64 = false;
  }
  int idx = blockIdx.x * 256 + threadIdx.x;
  if (idx >= E1) return;
  int s, d;
  if (idx < E) {
    if (is64) { s = (int)p64[idx]; d = (int)p64[E + idx]; }
    else      { s = p32[idx];      d = p32[E + idx]; }
  } else {
    s = d = idx - E;
  }
  esrc[idx] = s;
  edst[idx] = d;
  atomicAdd(&cnt1[d], 1);
  atomicAdd(&cnt2[s], 1);
}

// ---------------------------------------------------------------------------
// Shuffle-based single-block scan: 3 barriers per 1024-chunk (was ~30).
__device__ __forceinline__ void scan_one(const int* __restrict__ cnt,
                                         int* __restrict__ indptr,
                                         int* __restrict__ cur, int N, int* buf) {
  int t = threadIdx.x, lane = t & 63, w = t >> 6;
  int running = 0;
  for (int base = 0; base < N; base += 1024) {
    int v = (base + t < N) ? cnt[base + t] : 0;
    int incl = v;
#pragma unroll
    for (int off = 1; off < 64; off <<= 1) {
      int y = __shfl_up(incl, off);
      if (lane >= off) incl += y;
    }
    if (lane == 63) buf[w] = incl;
    __syncthreads();
    if (t < 16) {
      int x = buf[t];
#pragma unroll
      for (int off = 1; off < 16; off <<= 1) {
        int y = __shfl_up(x, off);
        if (t >= off) x += y;
      }
      buf[t] = x;
    }
    __syncthreads();
    int woff = w ? buf[w - 1] : 0;
    int tot = buf[15];
    if (base + t < N) {
      int excl = running + woff + incl - v;
      indptr[base + t] = excl;
      cur[base + t] = excl;
    }
    running += tot;
    __syncthreads();
  }
  if (t == 0) indptr[N] = running;
  __syncthreads();
}

__global__ __launch_bounds__(1024) void scan2_kernel(const int* cnt1, int* indptr1, int* cur1,
                                                     const int* cnt2, int* indptr2, int* cur2,
                                                     int N) {
  __shared__ int buf[16];
  scan_one(cnt1, indptr1, cur1, N, buf);
  scan_one(cnt2, indptr2, cur2, N, buf);
}

__global__ void scatter_edges(const int* __restrict__ esrc, const int* __restrict__ edst,
                              int* __restrict__ cur1, int* __restrict__ cur2,
                              int* __restrict__ eidx1, int* __restrict__ eidx2, int E1) {
  int e = blockIdx.x * 256 + threadIdx.x;
  if (e >= E1) return;
  int p1 = atomicAdd(&cur1[edst[e]], 1);
  eidx1[p1] = e;
  int p2 = atomicAdd(&cur2[esrc[e]], 1);
  eidx2[p2] = e;
}

// ---------------------------------------------------------------------------
// conv1: per-dst softmax (8 heads) + weighted aggregation of h1[src] (bf16, 2048).
// One block per dst; thread t owns channels [8t, 8t+8) -> head = t>>5.
__global__ __launch_bounds__(256) void conv1_agg(const unsigned short* __restrict__ h1,
                                                 const float* __restrict__ a_s,
                                                 const float* __restrict__ a_d,
                                                 const int* __restrict__ esrc,
                                                 const int* __restrict__ indptr,
                                                 const int* __restrict__ eidx,
                                                 const float* __restrict__ b1,
                                                 unsigned short* __restrict__ x2) {
  int dst = blockIdx.x, tid = threadIdx.x;
  int start = indptr[dst];
  int deg = indptr[dst + 1] - start;
  __shared__ float m_sh[8], d_sh[8];
  __shared__ float al_sh[64 * 8];
  __shared__ int src_sh[64];
  int lane = tid & 63, wave = tid >> 6;

  for (int h = wave; h < 8; h += 4) {
    float ad = a_d[dst * 8 + h];
    float mx = -1e30f;
    for (int j = lane; j < deg; j += 64) {
      int e = eidx[start + j];
      float ev = a_s[esrc[e] * 8 + h] + ad;
      ev = ev > 0.f ? ev : NEG_SLOPE * ev;
      mx = fmaxf(mx, ev);
    }
#pragma unroll
    for (int off = 32; off; off >>= 1) mx = fmaxf(mx, __shfl_down(mx, off));
    mx = __shfl(mx, 0);
    float sm = 0.f;
    for (int j = lane; j < deg; j += 64) {
      int e = eidx[start + j];
      float ev = a_s[esrc[e] * 8 + h] + ad;
      ev = ev > 0.f ? ev : NEG_SLOPE * ev;
      sm += __expf(ev - mx);
    }
#pragma unroll
    for (int off = 32; off; off >>= 1) sm += __shfl_down(sm, off);
    if (lane == 0) { m_sh[h] = mx; d_sh[h] = sm + 1e-16f; }
  }
  __syncthreads();

  float acc[8] = {0.f, 0.f, 0.f, 0.f, 0.f, 0.f, 0.f, 0.f};
  int myhead = tid >> 5;
  for (int base = 0; base < deg; base += 64) {
    int cnt = min(64, deg - base);
    for (int t = tid; t < cnt * 8; t += 256) {
      int j = t >> 3, h = t & 7;
      int e = eidx[start + base + j];
      int s = esrc[e];
      if (h == 0) src_sh[j] = s;
      float ev = a_s[s * 8 + h] + a_d[dst * 8 + h];
      ev = ev > 0.f ? ev : NEG_SLOPE * ev;
      al_sh[j * 8 + h] = __expf(ev - m_sh[h]) / d_sh[h];
    }
    __syncthreads();
    int j = 0;
    for (; j + 4 <= cnt; j += 4) {   // 4 outstanding 16B loads/lane
      float4 r0 = ((const float4*)(h1 + (size_t)src_sh[j + 0] * 2048))[tid];
      float4 r1 = ((const float4*)(h1 + (size_t)src_sh[j + 1] * 2048))[tid];
      float4 r2 = ((const float4*)(h1 + (size_t)src_sh[j + 2] * 2048))[tid];
      float4 r3 = ((const float4*)(h1 + (size_t)src_sh[j + 3] * 2048))[tid];
      float al0 = al_sh[(j + 0) * 8 + myhead];
      float al1 = al_sh[(j + 1) * 8 + myhead];
      float al2 = al_sh[(j + 2) * 8 + myhead];
      float al3 = al_sh[(j + 3) * 8 + myhead];
      const unsigned short* b0 = (const unsigned short*)&r0;
      const unsigned short* b1p = (const unsigned short*)&r1;
      const unsigned short* b2 = (const unsigned short*)&r2;
      const unsigned short* b3 = (const unsigned short*)&r3;
#pragma unroll
      for (int i = 0; i < 8; ++i) {
        acc[i] += al0 * bf2f(b0[i]);
        acc[i] += al1 * bf2f(b1p[i]);
        acc[i] += al2 * bf2f(b2[i]);
        acc[i] += al3 * bf2f(b3[i]);
      }
    }
    for (; j < cnt; ++j) {
      float al = al_sh[j * 8 + myhead];
      float4 r = ((const float4*)(h1 + (size_t)src_sh[j] * 2048))[tid];
      const unsigned short* rb = (const unsigned short*)&r;
#pragma unroll
      for (int i = 0; i < 8; ++i) acc[i] += al * bf2f(rb[i]);
    }
    __syncthreads();
  }

  unsigned short outv[8];
#pragma unroll
  for (int i = 0; i < 8; ++i) {
    float v = acc[i] + b1[tid * 8 + i];
    outv[i] = f2bf(fmaxf(v, 0.f));
  }
  *((float4*)(x2 + (size_t)dst * 2048 + tid * 8)) = *((const float4*)outv);
}

// ---------------------------------------------------------------------------
// conv2: 1 head, 256-wide f32 in, bf16 out (for MFMA out-proj).
__global__ __launch_bounds__(256) void conv2_agg(const float* __restrict__ h2,
                                                 const float* __restrict__ a_s,
                                                 const float* __restrict__ a_d,
                                                 const int* __restrict__ other,
                                                 const int* __restrict__ indptr,
                                                 const int* __restrict__ eidx,
                                                 const float* __restrict__ b2,
                                                 unsigned short* __restrict__ x3) {
  int dst = blockIdx.x, tid = threadIdx.x;
  int start = indptr[dst];
  int deg = indptr[dst + 1] - start;
  __shared__ float md[2];
  __shared__ float al_sh[64];
  __shared__ int src_sh[64];
  int lane = tid & 63, wave = tid >> 6;

  if (wave == 0) {
    float ad = a_d[dst];
    float mx = -1e30f;
    for (int j = lane; j < deg; j += 64) {
      float ev = a_s[other[eidx[start + j]]] + ad;
      ev = ev > 0.f ? ev : NEG_SLOPE * ev;
      mx = fmaxf(mx, ev);
    }
#pragma unroll
    for (int off = 32; off; off >>= 1) mx = fmaxf(mx, __shfl_down(mx, off));
    mx = __shfl(mx, 0);
    float sm = 0.f;
    for (int j = lane; j < deg; j += 64) {
      float ev = a_s[other[eidx[start + j]]] + ad;
      ev = ev > 0.f ? ev : NEG_SLOPE * ev;
      sm += __expf(ev - mx);
    }
#pragma unroll
    for (int off = 32; off; off >>= 1) sm += __shfl_down(sm, off);
    if (lane == 0) { md[0] = mx; md[1] = sm + 1e-16f; }
  }
  __syncthreads();
  float mx = md[0], dn = md[1];
  float acc = 0.f;
  for (int base = 0; base < deg; base += 64) {
    int cnt = min(64, deg - base);
    if (tid < cnt) {
      int s = other[eidx[start + base + tid]];
      float ev = a_s[s] + a_d[dst];
      ev = ev > 0.f ? ev : NEG_SLOPE * ev;
      al_sh[tid] = __expf(ev - mx) / dn;
      src_sh[tid] = s;
    }
    __syncthreads();
    for (int j = 0; j < cnt; ++j)
      acc += al_sh[j] * h2[(size_t)src_sh[j] * 256 + tid];
    __syncthreads();
  }
  float v = acc + b2[tid];
  x3[(size_t)dst * 256 + tid] = f2bf(fmaxf(v, 0.f));
}

// ---------------------------------------------------------------------------
extern "C" void kernel_launch(void* const* d_in, const int* in_sizes, int n_in,
                              void* d_out, int out_size, void* d_ws, size_t ws_size,
                              hipStream_t stream) {
  (void)n_in; (void)out_size; (void)ws_size;
  const float* constraints = (const float*)d_in[0];
  const float* columns     = (const float*)d_in[1];
  const void*  edges       = d_in[2];
  const float* W_node = (const float*)d_in[3];
  const float* b_node = (const float*)d_in[4];
  const float* W_col  = (const float*)d_in[5];
  const float* b_col  = (const float*)d_in[6];
  const float* W1       = (const float*)d_in[7];
  const float* att_src1 = (const float*)d_in[8];
  const float* att_dst1 = (const float*)d_in[9];
  const float* b1       = (const float*)d_in[10];
  const float* W2       = (const float*)d_in[11];
  const float* att_src2 = (const float*)d_in[12];
  const float* att_dst2 = (const float*)d_in[13];
  const float* b2       = (const float*)d_in[14];
  const float* W_out    = (const float*)d_in[15];
  const float* b_out    = (const float*)d_in[16];

  const int Nc   = in_sizes[0] / 64;
  const int Ncol = in_sizes[1] / 128;
  const int E    = in_sizes[2] / 2;
  const int N    = Nc + Ncol;
  const int E1   = E + N;

  char* p = (char*)d_ws;
  size_t off = 0;
  auto alloc = [&](size_t nbytes) -> void* {
    void* r = p + off;
    off = (off + nbytes + 255) & ~(size_t)255;
    return r;
  };
  unsigned short* Wn_b  = (unsigned short*)alloc(2ull * 256 * 64);
  unsigned short* Wc_b  = (unsigned short*)alloc(2ull * 256 * 128);
  unsigned short* W1b   = (unsigned short*)alloc(2ull * 2048 * 256);
  unsigned short* W2b   = (unsigned short*)alloc(2ull * 256 * 2048);
  unsigned short* Woutb = (unsigned short*)alloc(2ull * 128 * 256);
  unsigned short* consb = (unsigned short*)alloc(2ull * (size_t)Nc * 64);
  unsigned short* colsb = (unsigned short*)alloc(2ull * (size_t)Ncol * 128);
  unsigned short* xb    = (unsigned short*)alloc(2ull * (size_t)N * 256);
  unsigned short* h1    = (unsigned short*)alloc(2ull * (size_t)N * 2048);
  float* a_s1 = (float*)alloc(sizeof(float) * (size_t)N * 8);
  float* a_d1 = (float*)alloc(sizeof(float) * (size_t)N * 8);
  int* esrc = (int*)alloc(4ull * E1);
  int* edst = (int*)alloc(4ull * E1);
  int* cnt1 = (int*)alloc(4ull * 2 * N);
  int* cnt2 = cnt1 + N;
  int* indptr1 = (int*)alloc(4ull * (N + 1));
  int* cur1    = (int*)alloc(4ull * N);
  int* indptr2 = (int*)alloc(4ull * (N + 1));
  int* cur2    = (int*)alloc(4ull * N);
  int* eidx1 = (int*)alloc(4ull * E1);
  int* eidx2 = (int*)alloc(4ull * E1);
  unsigned short* x2 = (unsigned short*)alloc(2ull * (size_t)N * 2048);
  float* h2 = (float*)alloc(sizeof(float) * (size_t)N * 256);
  float* a_s2 = (float*)alloc(sizeof(float) * (size_t)N);
  float* a_d2 = (float*)alloc(sizeof(float) * (size_t)N);
  unsigned short* x3 = (unsigned short*)alloc(2ull * (size_t)N * 256);

  hipMemsetAsync(cnt1, 0, 4ull * 2 * N, stream);
  prep<<<1024, 256, 0, stream>>>(W_node, W_col, W1, W2, W_out, constraints, columns,
                                 Wn_b, Wc_b, W1b, W2b, Woutb, consb, colsb,
                                 Nc * 64, Ncol * 128);

  // encoder (MFMA, bf16 out -> xb)
  gemm_mfma_bt<true, true, true><<<dim3(2, (Nc + 127) / 128), 256, 0, stream>>>(
      consb, Wn_b, b_node, xb, Nc, 64, 256);
  gemm_mfma_bt<true, true, true><<<dim3(2, (Ncol + 127) / 128), 256, 0, stream>>>(
      colsb, Wc_b, b_col, xb + (size_t)Nc * 256, Ncol, 128, 256);

  // conv1 projection + attention dots
  gemm_mfma_bt<true, false, false><<<dim3(16, (N + 127) / 128), 256, 0, stream>>>(
      xb, W1b, nullptr, h1, N, 256, 2048);
  att_dots<true><<<(N * 8 + 3) / 4, 256, 0, stream>>>(h1, att_src1, att_dst1, a_s1, a_d1, N, 8);

  // graph CSR (both directions)
  build_count<<<(E1 + 255) / 256, 256, 0, stream>>>(edges, E, N, esrc, edst, cnt1, cnt2, E1);
  scan2_kernel<<<1, 1024, 0, stream>>>(cnt1, indptr1, cur1, cnt2, indptr2, cur2, N);
  scatter_edges<<<(E1 + 255) / 256, 256, 0, stream>>>(esrc, edst, cur1, cur2, eidx1, eidx2, E1);

  // conv1 aggregate -> x2 (bf16), then conv2 projection (32x256-tile MFMA)
  conv1_agg<<<N, 256, 0, stream>>>(h1, a_s1, a_d1, esrc, indptr1, eidx1, b1, x2);
  gemm_mfma_k2048<<<(N + 31) / 32, 256, 0, stream>>>(x2, W2b, h2, N, 2048);
  att_dots<false><<<(N + 3) / 4, 256, 0, stream>>>(h2, att_src2, att_dst2, a_s2, a_d2, N, 1);
  conv2_agg<<<N, 256, 0, stream>>>(h2, a_s2, a_d2, edst, indptr2, eidx2, b2, x3);

  // output projection (rows Nc..N) -> d_out f32
  gemm_mfma_bt<false, true, false><<<dim3(1, (Ncol + 127) / 128), 256, 0, stream>>>(
      x3 + (size_t)Nc * 256, Woutb, b_out, (float*)d_out, Ncol, 256, 128);
}